// Round 3
// baseline (244.915 us; speedup 1.0000x reference)
//
#include <hip/hip_runtime.h>

#define BLOCK 256
#define PTS_PER_BLOCK 512          // 2 points per thread
#define NPTS (8 * 65536)
#define REP 16                     // CALIBRATION: replicate MLP phase 16x

// CALIBRATION PROBE — not a perf candidate.
// Identical outputs to R2 kernel: the MLP loop runs REP times; each rep's
// inputs pass through an identity asm (blocks CSE across reps), each rep's
// results are kept live via asm (blocks DCE of reps 0..REP-2). Last rep's
// values are stored. Purpose: surface the kernel in rocprof top-5 with its
// own dur/VALUBusy/Occupancy, and measure the harness floor
// (floor = dur_us - kernel_dur).

__global__ __launch_bounds__(BLOCK, 4) void cubeflow_fused(
    const float* __restrict__ input,
    const float* __restrict__ latent,
    const float* __restrict__ W1,
    const float* __restrict__ b1,
    const float* __restrict__ W2,
    const float* __restrict__ b2,
    float* __restrict__ out)
{
    const int t     = threadIdx.x;
    const int base  = blockIdx.x * PTS_PER_BLOCK;
    const int batch = base >> 16;                 // 128 blocks per batch
    const float theta = latent[batch] * 10.0f;    // uniform per block

    // ---- load this thread's 2 points: 3x float2 (8B aligned) ----
    const int p0 = base + 2 * t;
    const float2* ip = reinterpret_cast<const float2*>(input + 3 * p0);
    const float2 f0 = ip[0];
    const float2 f1 = ip[1];
    const float2 f2 = ip[2];
    const float x0a = f0.x, x1a = f0.y, x2a = f1.x;
    const float x0b = f1.y, x1b = f2.x, x2b = f2.y;

    float* __restrict__ out_eval  = out;             // NPTS
    float* __restrict__ out_con   = out + NPTS;      // NPTS*4
    float* __restrict__ out_probs = out + 5 * NPTS;  // NPTS*2

    // ---- eval + con (fp32, exact) ----
    {
        const float cth = cosf(theta);
        const float sth = sinf(theta);

        const float d0a = x0a - theta, d1a = x1a, d2a = x2a;
        const float d0b = x0b - theta, d1b = x1b, d2b = x2b;

        const float f1a = fmaf(1.4f * d0a, d0a, fmaf(1.4f * d1a, d1a, 0.2f * d2a * d2a)) - 0.5f;
        const float f1b = fmaf(1.4f * d0b, d0b, fmaf(1.4f * d1b, d1b, 0.2f * d2b * d2b)) - 0.5f;

        const float c2xa = fmaf(cth, d0a,  sth * d1a);
        const float c2ya = fmaf(cth, d1a, -sth * d0a);
        const float c2za = d2a + 0.4f;
        const float f2a = fmaf(3.8f * c2xa, c2xa, fmaf(0.6f * c2ya, c2ya, 3.8f * c2za * c2za)) - 0.5f;
        const float c2xb = fmaf(cth, d0b,  sth * d1b);
        const float c2yb = fmaf(cth, d1b, -sth * d0b);
        const float c2zb = d2b + 0.4f;
        const float f2b = fmaf(3.8f * c2xb, c2xb, fmaf(0.6f * c2yb, c2yb, 3.8f * c2zb * c2zb)) - 0.5f;

        const float c3xa = fmaf(cth, d0a, -sth * d1a);
        const float c3ya = fmaf(sth, d0a,  cth * d1a);
        const float c3za = d2a - 0.6f;
        const float f3a = fmaf(0.35f * c3xa, c3xa, fmaf(2.8f * c3ya, c3ya, 2.8f * c3za * c3za)) - 0.5f;
        const float c3xb = fmaf(cth, d0b, -sth * d1b);
        const float c3yb = fmaf(sth, d0b,  cth * d1b);
        const float c3zb = d2b - 0.6f;
        const float f3b = fmaf(0.35f * c3xb, c3xb, fmaf(2.8f * c3yb, c3yb, 2.8f * c3zb * c3zb)) - 0.5f;

        *reinterpret_cast<float2*>(out_eval + p0) =
            make_float2(fminf(f1a, fminf(f2a, f3a)), fminf(f1b, fminf(f2b, f3b)));

        float4* cp = reinterpret_cast<float4*>(out_con + 4 * p0);
        cp[0] = make_float4(x0a, x1a, x2a, theta);
        cp[1] = make_float4(x0b, x1b, x2b, theta);
    }

    // ---- MLP replicated REP times (calibration) ----
    float a0a = 0.0f, a1a = 0.0f, a0b = 0.0f, a1b = 0.0f;
#pragma unroll 1
    for (int rep = 0; rep < REP; ++rep) {
        // identity pass-through: blocks CSE of the rep bodies
        float u0a = x0a, u1a = x1a, u2a = x2a;
        float u0b = x0b, u1b = x1b, u2b = x2b;
        asm volatile("" : "+v"(u0a), "+v"(u1a), "+v"(u2a),
                          "+v"(u0b), "+v"(u1b), "+v"(u2b));

        float t0 = 0.0f, t1 = 0.0f, t2 = 0.0f, t3 = 0.0f;
#pragma unroll 8
        for (int h = 0; h < 128; ++h) {
            const float w0 = W1[4 * h + 0];        // uniform weight loads
            const float w1 = W1[4 * h + 1];
            const float w2 = W1[4 * h + 2];
            const float w3 = W1[4 * h + 3];
            const float bias = fmaf(theta, w3, b1[h]);
            const float w20 = W2[h];
            const float w21 = W2[128 + h];

            float hva = fmaf(u0a, w0, fmaf(u1a, w1, fmaf(u2a, w2, bias)));
            float hvb = fmaf(u0b, w0, fmaf(u1b, w1, fmaf(u2b, w2, bias)));
            hva = fmaxf(hva, 0.0f);
            hvb = fmaxf(hvb, 0.0f);
            t0 = fmaf(hva, w20, t0);
            t1 = fmaf(hva, w21, t1);
            t2 = fmaf(hvb, w20, t2);
            t3 = fmaf(hvb, w21, t3);
        }
        // keep this rep's results live: blocks DCE of reps 0..REP-2
        asm volatile("" :: "v"(t0), "v"(t1), "v"(t2), "v"(t3));
        a0a = t0; a1a = t1; a0b = t2; a1b = t3;
    }

    const float B0 = b2[0];
    const float B1 = b2[1];
    *reinterpret_cast<float4*>(out_probs + 2 * p0) =
        make_float4(a0a + B0, a1a + B1, a0b + B0, a1b + B1);
}

extern "C" void kernel_launch(void* const* d_in, const int* in_sizes, int n_in,
                              void* d_out, int out_size, void* d_ws, size_t ws_size,
                              hipStream_t stream) {
    const float* input  = (const float*)d_in[0];
    const float* latent = (const float*)d_in[1];
    const float* W1     = (const float*)d_in[2];
    const float* b1     = (const float*)d_in[3];
    const float* W2     = (const float*)d_in[4];
    const float* b2     = (const float*)d_in[5];
    float* out = (float*)d_out;

    const int nblocks = NPTS / PTS_PER_BLOCK;   // 1024
    hipLaunchKernelGGL(cubeflow_fused, dim3(nblocks), dim3(BLOCK), 0, stream,
                       input, latent, W1, b1, W2, b2, out);
}

// Round 4
// 87.347 us; speedup vs baseline: 2.8039x; 2.8039x over previous
//
#include <hip/hip_runtime.h>

#define NPTS (8 * 65536)
#define NBATCH 8
#define NH 128

// ---------------------------------------------------------------------------
// Pre-kernel: fold bias table biasTab[b][h] = b1[h] + (latent[b]*10)*W1[h][3]
// into workspace (4 KB). One tiny block; runs in ~2 us, removes the per-h
// bias fold (v_mov + v_fma) from every thread of the main kernel.
// ---------------------------------------------------------------------------
__global__ void cubeflow_prep(
    const float* __restrict__ latent,
    const float* __restrict__ W1,
    const float* __restrict__ b1,
    float* __restrict__ biasTab)
{
    const int h = threadIdx.x;          // 0..127
    if (h < NH) {
        const float w3 = W1[4 * h + 3];
        const float bb = b1[h];
#pragma unroll
        for (int b = 0; b < NBATCH; ++b) {
            biasTab[b * NH + h] = fmaf(latent[b] * 10.0f, w3, bb);
        }
    }
}

// ---------------------------------------------------------------------------
// Main kernel: 1 point per thread, 2048 blocks x 256 threads.
// 8 blocks/CU -> 32 waves/CU (100% of the 2048-thread/CU cap), 8 waves/SIMD —
// the R3 calibration showed R2 was ~80% un-hidden latency at 2.4-4 waves/SIMD.
// All weights/biases read wave-uniform (batch derived from blockIdx only) ->
// s_load through the scalar cache; no LDS, no barrier.
// ---------------------------------------------------------------------------
__global__ __launch_bounds__(256, 8) void cubeflow_main(
    const float* __restrict__ input,
    const float* __restrict__ latent,
    const float* __restrict__ W1,
    const float* __restrict__ W2,
    const float* __restrict__ b2,
    const float* __restrict__ biasTab,
    float* __restrict__ out)
{
    const int t     = threadIdx.x;
    const int p     = blockIdx.x * 256 + t;
    const int batch = blockIdx.x >> 8;            // provably uniform (SGPR)
    const float theta = latent[batch] * 10.0f;

    // ---- load this thread's point (3 coalesced dword loads, stride 12B) ----
    const float* ip = input + 3 * p;
    const float x0 = ip[0];
    const float x1 = ip[1];
    const float x2 = ip[2];

    float* __restrict__ out_eval  = out;             // NPTS
    float* __restrict__ out_con   = out + NPTS;      // NPTS*4
    float* __restrict__ out_probs = out + 5 * NPTS;  // NPTS*2

    // ---- eval + con (fp32, exact) ----
    {
        const float cth = cosf(theta);
        const float sth = sinf(theta);

        const float d0 = x0 - theta, d1 = x1, d2 = x2;

        const float f1 = fmaf(1.4f * d0, d0, fmaf(1.4f * d1, d1, 0.2f * d2 * d2)) - 0.5f;

        const float c2x = fmaf(cth, d0,  sth * d1);
        const float c2y = fmaf(cth, d1, -sth * d0);
        const float c2z = d2 + 0.4f;
        const float f2 = fmaf(3.8f * c2x, c2x, fmaf(0.6f * c2y, c2y, 3.8f * c2z * c2z)) - 0.5f;

        const float c3x = fmaf(cth, d0, -sth * d1);
        const float c3y = fmaf(sth, d0,  cth * d1);
        const float c3z = d2 - 0.6f;
        const float f3 = fmaf(0.35f * c3x, c3x, fmaf(2.8f * c3y, c3y, 2.8f * c3z * c3z)) - 0.5f;

        out_eval[p] = fminf(f1, fminf(f2, f3));
        *reinterpret_cast<float4*>(out_con + 4 * p) = make_float4(x0, x1, x2, theta);
    }

    // ---- MLP: 128 hidden units, all weights via s_load (wave-uniform) ----
    const float* __restrict__ bt = biasTab + batch * NH;
    float a0 = 0.0f, a1 = 0.0f;
#pragma unroll 8
    for (int h = 0; h < NH; ++h) {
        const float w0   = W1[4 * h + 0];     // s_load (merged dwordx16/group)
        const float w1   = W1[4 * h + 1];
        const float w2   = W1[4 * h + 2];
        const float bias = bt[h];             // s_load (pre-folded)
        const float w20  = W2[h];
        const float w21  = W2[NH + h];

        float hv = fmaf(x0, w0, fmaf(x1, w1, fmaf(x2, w2, bias)));
        hv = fmaxf(hv, 0.0f);
        a0 = fmaf(hv, w20, a0);
        a1 = fmaf(hv, w21, a1);
    }

    *reinterpret_cast<float2*>(out_probs + 2 * p) =
        make_float2(a0 + b2[0], a1 + b2[1]);
}

extern "C" void kernel_launch(void* const* d_in, const int* in_sizes, int n_in,
                              void* d_out, int out_size, void* d_ws, size_t ws_size,
                              hipStream_t stream) {
    const float* input  = (const float*)d_in[0];
    const float* latent = (const float*)d_in[1];
    const float* W1     = (const float*)d_in[2];
    const float* b1     = (const float*)d_in[3];
    const float* W2     = (const float*)d_in[4];
    const float* b2     = (const float*)d_in[5];
    float* out     = (float*)d_out;
    float* biasTab = (float*)d_ws;               // 8*128*4 = 4 KB

    hipLaunchKernelGGL(cubeflow_prep, dim3(1), dim3(128), 0, stream,
                       latent, W1, b1, biasTab);

    const int nblocks = NPTS / 256;              // 2048
    hipLaunchKernelGGL(cubeflow_main, dim3(nblocks), dim3(256), 0, stream,
                       input, latent, W1, W2, b2, biasTab, out);
}

// Round 5
// 82.416 us; speedup vs baseline: 2.9717x; 1.0598x over previous
//
#include <hip/hip_runtime.h>

#define NPTS (8 * 65536)

// R5: amortize the lockstep fixed costs over 4 unique points/thread.
// 512 blocks x 256 threads, each block owns 1024 points (lane-major:
// p[k] = base + t + 256k -> all global IO stays perfectly lane-contiguous).
// Weights via wave-uniform s_load (scalar cache); bias b1+theta*w3 folded
// inline (~2 VALU/h, amortized over 4 points). No LDS, no barrier, no
// prep kernel. Per-wave VALU issue ~7k cyc vs ~2-5k cyc of one-time
// stalls -> stalls amortize instead of dominating.

__global__ __launch_bounds__(256, 8) void cubeflow_fused(
    const float* __restrict__ input,
    const float* __restrict__ latent,
    const float* __restrict__ W1,
    const float* __restrict__ b1,
    const float* __restrict__ W2,
    const float* __restrict__ b2,
    float* __restrict__ out)
{
    const int t     = threadIdx.x;
    const int base  = blockIdx.x * 1024;          // 512 blocks
    const int batch = base >> 16;                 // 64 blocks per batch
    const float theta = latent[batch] * 10.0f;    // uniform per block (SGPR)

    // ---- load 4 points (lane-major, coalesced) ----
    float x0[4], x1[4], x2[4];
    int p[4];
#pragma unroll
    for (int k = 0; k < 4; ++k) {
        p[k] = base + t + 256 * k;
        const float* ip = input + 3 * p[k];
        x0[k] = ip[0];
        x1[k] = ip[1];
        x2[k] = ip[2];
    }

    float* __restrict__ out_eval  = out;             // NPTS
    float* __restrict__ out_con   = out + NPTS;      // NPTS*4
    float* __restrict__ out_probs = out + 5 * NPTS;  // NPTS*2

    // ---- eval + con (fp32, exact) ----
    {
        const float cth = cosf(theta);
        const float sth = sinf(theta);
#pragma unroll
        for (int k = 0; k < 4; ++k) {
            const float d0 = x0[k] - theta;
            const float d1 = x1[k];
            const float d2 = x2[k];
            const float f1 = fmaf(1.4f * d0, d0, fmaf(1.4f * d1, d1, 0.2f * d2 * d2)) - 0.5f;
            const float c2x = fmaf(cth, d0,  sth * d1);
            const float c2y = fmaf(cth, d1, -sth * d0);
            const float c2z = d2 + 0.4f;
            const float f2 = fmaf(3.8f * c2x, c2x, fmaf(0.6f * c2y, c2y, 3.8f * c2z * c2z)) - 0.5f;
            const float c3x = fmaf(cth, d0, -sth * d1);
            const float c3y = fmaf(sth, d0,  cth * d1);
            const float c3z = d2 - 0.6f;
            const float f3 = fmaf(0.35f * c3x, c3x, fmaf(2.8f * c3y, c3y, 2.8f * c3z * c3z)) - 0.5f;
            out_eval[p[k]] = fminf(f1, fminf(f2, f3));
            *reinterpret_cast<float4*>(out_con + 4 * p[k]) =
                make_float4(x0[k], x1[k], x2[k], theta);
        }
    }

    // ---- MLP: 128 hidden units x 4 points, weights via s_load ----
    float a0[4], a1[4];
    {
        const float B0 = b2[0];
        const float B1 = b2[1];
#pragma unroll
        for (int k = 0; k < 4; ++k) { a0[k] = B0; a1[k] = B1; }
    }

#pragma unroll 8
    for (int h = 0; h < 128; ++h) {
        const float w0   = W1[4 * h + 0];     // uniform -> s_load (merged)
        const float w1   = W1[4 * h + 1];
        const float w2   = W1[4 * h + 2];
        const float bias = fmaf(theta, W1[4 * h + 3], b1[h]);
        const float w20  = W2[h];
        const float w21  = W2[128 + h];
#pragma unroll
        for (int k = 0; k < 4; ++k) {
            float hv = fmaf(x0[k], w0, fmaf(x1[k], w1, fmaf(x2[k], w2, bias)));
            hv = fmaxf(hv, 0.0f);
            a0[k] = fmaf(hv, w20, a0[k]);
            a1[k] = fmaf(hv, w21, a1[k]);
        }
    }

#pragma unroll
    for (int k = 0; k < 4; ++k) {
        *reinterpret_cast<float2*>(out_probs + 2 * p[k]) = make_float2(a0[k], a1[k]);
    }
}

extern "C" void kernel_launch(void* const* d_in, const int* in_sizes, int n_in,
                              void* d_out, int out_size, void* d_ws, size_t ws_size,
                              hipStream_t stream) {
    const float* input  = (const float*)d_in[0];
    const float* latent = (const float*)d_in[1];
    const float* W1     = (const float*)d_in[2];
    const float* b1     = (const float*)d_in[3];
    const float* W2     = (const float*)d_in[4];
    const float* b2     = (const float*)d_in[5];
    float* out = (float*)d_out;

    const int nblocks = NPTS / 1024;   // 512
    hipLaunchKernelGGL(cubeflow_fused, dim3(nblocks), dim3(256), 0, stream,
                       input, latent, W1, b1, W2, b2, out);
}